// Round 1
// baseline (14092.203 us; speedup 1.0000x reference)
//
#include <hip/hip_runtime.h>

// LSTM 2-layer fused persistent kernel, full fp32.
// Decomposition: 256 workgroups (1 per batch row, 1 per CU), 512 threads
// (thread g owns gate row g of 4H=512). Recurrence is batch-independent ->
// no inter-WG sync. Weights register-resident per phase:
//   layer0 phase: W_ih0 row (64 f32) + W_hh0 row (128 f32) = 192 VGPR
//   layer1 phase: W_hh1 row (128 f32) + 32 xp accumulators
// W_ih1 projection handled as per-sub-chunk mini-GEMM (32 steps batched) so
// layer1 never needs 256 weight regs. T processed in 16 chunks of 64 steps;
// h0 chunk lives in LDS; weight sets reload from L2 per chunk-phase.
// Zero d_ws usage.

#define NB   256
#define TSEQ 1024
#define II   64
#define HH   128
#define G4   512
#define TC   64          // steps per chunk
#define SC   32          // layer-1 sub-chunk (xp accumulators in regs)
#define NCHUNK (TSEQ/TC)

__device__ __forceinline__ float sigm(float x) {
    return 1.f / (1.f + __expf(-x));
}
__device__ __forceinline__ float tanh_f(float x) {
    float ax = fabsf(x);
    float e  = __expf(2.f * ax);
    float t  = 1.f - 2.f / (e + 1.f);
    return copysignf(t, x);
}

__global__ __launch_bounds__(512, 2)
void lstm_all(const float* __restrict__ x,
              const float* __restrict__ Wih0, const float* __restrict__ Whh0,
              const float* __restrict__ bih0, const float* __restrict__ bhh0,
              const float* __restrict__ Wih1, const float* __restrict__ Whh1,
              const float* __restrict__ bih1, const float* __restrict__ bhh1,
              const float* __restrict__ Wlin, const float* __restrict__ blin,
              float* __restrict__ out)
{
    const int b = blockIdx.x;
    const int g = threadIdx.x;   // gate row 0..511

    __shared__ __align__(16) float h0buf[TC + 1][HH];  // 33,280 B (slot 0 = carry)
    __shared__ __align__(16) float xc[TC][II];         // 16,384 B
    __shared__ __align__(16) float xp1[SC][G4];        // 65,536 B
    __shared__ __align__(16) float gates[G4];          //  2,048 B
    __shared__ __align__(16) float h1buf[HH];          //    512 B
    // total ~117.8 KB < 160 KB

    float c0 = 0.f, c1 = 0.f;                  // cell states (threads < HH)
    const float bias0 = bih0[g] + bhh0[g];
    const float bias1 = bih1[g] + bhh1[g];
    const bool  is_tanh_gate = (g >= 2 * HH) && (g < 3 * HH);  // wave-uniform

    if (g < HH) { h0buf[0][g] = 0.f; h1buf[g] = 0.f; }
    __syncthreads();

    const float* xb = x + (size_t)b * TSEQ * II;

    for (int ch = 0; ch < NCHUNK; ++ch) {
        // ==================== layer 0 phase ====================
        float4 w0[II / 4], wh0[HH / 4];
        {
            const float4* p = (const float4*)(Wih0 + (size_t)g * II);
            #pragma unroll
            for (int i = 0; i < II / 4; ++i) w0[i] = p[i];
            const float4* q = (const float4*)(Whh0 + (size_t)g * HH);
            #pragma unroll
            for (int i = 0; i < HH / 4; ++i) wh0[i] = q[i];
        }
        {   // stage x[b, ch*TC : ch*TC+TC, :] (contiguous 16 KB, coalesced)
            const float4* src = (const float4*)(xb + (size_t)ch * TC * II);
            float4* dst = (float4*)&xc[0][0];
            dst[g]       = src[g];
            dst[g + 512] = src[g + 512];
        }
        if (ch > 0 && g < HH) h0buf[0][g] = h0buf[TC][g];  // carry h0
        __syncthreads();

        #pragma unroll 1
        for (int t = 0; t < TC; ++t) {
            // gate_g = bias0 + W_ih0[g,:]·x_t + W_hh0[g,:]·h0_{t-1}
            float ax = 0.f, ay = 0.f, az = 0.f, aw = 0.f;  // 4 indep chains
            const float4* xv = (const float4*)&xc[t][0];
            #pragma unroll
            for (int i = 0; i < II / 4; ++i) {
                float4 v = xv[i];
                ax += w0[i].x * v.x; ay += w0[i].y * v.y;
                az += w0[i].z * v.z; aw += w0[i].w * v.w;
            }
            const float4* hv = (const float4*)&h0buf[t][0];
            #pragma unroll
            for (int i = 0; i < HH / 4; ++i) {
                float4 v = hv[i];
                ax += wh0[i].x * v.x; ay += wh0[i].y * v.y;
                az += wh0[i].z * v.z; aw += wh0[i].w * v.w;
            }
            float acc = bias0 + ((ax + ay) + (az + aw));
            gates[g] = is_tanh_gate ? tanh_f(acc) : sigm(acc);
            __syncthreads();
            if (g < HH) {
                float iv = gates[g],        fv = gates[HH + g];
                float gv = gates[2*HH + g], ov = gates[3*HH + g];
                c0 = fv * c0 + iv * gv;
                h0buf[t + 1][g] = ov * tanh_f(c0);
            }
            __syncthreads();
        }

        // ==================== layer 1 phase ====================
        float4 wh1[HH / 4];
        {
            const float4* q = (const float4*)(Whh1 + (size_t)g * HH);
            #pragma unroll
            for (int i = 0; i < HH / 4; ++i) wh1[i] = q[i];
        }
        const float4* pih1 = (const float4*)(Wih1 + (size_t)g * HH);

        #pragma unroll 1
        for (int sub = 0; sub < TC / SC; ++sub) {
            const int ts = sub * SC;
            // mini-GEMM: xp[tt] = W_ih1[g,:]·h0[ts+tt,:]  for tt in [0,SC)
            float xpacc[SC];
            #pragma unroll
            for (int i = 0; i < SC; ++i) xpacc[i] = 0.f;
            #pragma unroll 1
            for (int k4 = 0; k4 < HH / 4; ++k4) {
                const float4 w = pih1[k4];          // L1/L2-hot reload
                #pragma unroll
                for (int tt = 0; tt < SC; ++tt) {
                    const float4 v = *(const float4*)&h0buf[ts + tt + 1][k4 * 4];
                    xpacc[tt] += w.x * v.x + w.y * v.y + w.z * v.z + w.w * v.w;
                }
            }
            #pragma unroll
            for (int tt = 0; tt < SC; ++tt) xp1[tt][g] = xpacc[tt];
            __syncthreads();

            #pragma unroll 1
            for (int tt = 0; tt < SC; ++tt) {
                float ax = 0.f, ay = 0.f, az = 0.f, aw = 0.f;
                const float4* hv = (const float4*)&h1buf[0];
                #pragma unroll
                for (int i = 0; i < HH / 4; ++i) {
                    float4 v = hv[i];
                    ax += wh1[i].x * v.x; ay += wh1[i].y * v.y;
                    az += wh1[i].z * v.z; aw += wh1[i].w * v.w;
                }
                float acc = bias1 + xp1[tt][g] + ((ax + ay) + (az + aw));
                gates[g] = is_tanh_gate ? tanh_f(acc) : sigm(acc);
                __syncthreads();
                if (g < HH) {
                    float iv = gates[g],        fv = gates[HH + g];
                    float gv = gates[2*HH + g], ov = gates[3*HH + g];
                    c1 = fv * c1 + iv * gv;
                    h1buf[g] = ov * tanh_f(c1);
                }
                __syncthreads();
            }
        }
    }

    // final: out[b] = h1_{T-1} · W_lin[0,:] + b_lin   (wave 0 reduce)
    if (g < 64) {
        float s = h1buf[g] * Wlin[g] + h1buf[g + 64] * Wlin[g + 64];
        #pragma unroll
        for (int off = 32; off; off >>= 1) s += __shfl_down(s, off);
        if (g == 0) out[b] = s + blin[0];
    }
}

extern "C" void kernel_launch(void* const* d_in, const int* in_sizes, int n_in,
                              void* d_out, int out_size, void* d_ws, size_t ws_size,
                              hipStream_t stream)
{
    const float* x    = (const float*)d_in[0];
    const float* Wih0 = (const float*)d_in[1];
    const float* Whh0 = (const float*)d_in[2];
    const float* bih0 = (const float*)d_in[3];
    const float* bhh0 = (const float*)d_in[4];
    const float* Wih1 = (const float*)d_in[5];
    const float* Whh1 = (const float*)d_in[6];
    const float* bih1 = (const float*)d_in[7];
    const float* bhh1 = (const float*)d_in[8];
    const float* Wlin = (const float*)d_in[9];
    const float* blin = (const float*)d_in[10];
    float* out = (float*)d_out;

    hipLaunchKernelGGL(lstm_all, dim3(NB), dim3(512), 0, stream,
                       x, Wih0, Whh0, bih0, bhh0,
                       Wih1, Whh1, bih1, bhh1, Wlin, blin, out);
}